// Round 1
// baseline (1907.384 us; speedup 1.0000x reference)
//
#include <hip/hip_runtime.h>
#include <cmath>

// GNNCASimple: x:[N,128] -> enc MLP -> h:[N,256] -> msg GEMM -> m:[N,256]
// -> segment_sum over E edges -> aggr:[N,256] -> dec(cat(aggr,h)) -> out:[N,128]
// N=50000, E=400000, D=128, H=256, steps=1 (static).

#define TS 64
#define KC 16
#define LDSS 68   // padded leading dim (floats); 68*4B = 272B, 16B-aligned rows

// C[N,M] = act(A[N,K] @ W[M,K]^T + bias), where A is logically the
// concatenation of A0 (cols [0,K0)) and A1 (cols [K0,K)). For non-concat
// inputs pass K0 == K (A1 unused). ACT: 0=none, 1=relu, 2=tanh.
template <int ACT>
__global__ __launch_bounds__(256) void gemm_bias_act(
    const float* __restrict__ A0, const float* __restrict__ A1,
    const int K0, const int K,
    const float* __restrict__ W, const float* __restrict__ bias,
    float* __restrict__ C, const int N, const int M)
{
    __shared__ float As[KC][LDSS];
    __shared__ float Ws[KC][LDSS];

    const int t    = threadIdx.x;
    const int col0 = blockIdx.x * TS;
    const int row0 = blockIdx.y * TS;

    // loader mapping: each thread loads one float4 of A-tile and W-tile
    const int lr = t >> 2;   // 0..63  (row within tile)
    const int lq = t & 3;    // 0..3   (k-quad within 16-wide chunk)
    // compute mapping: 16x16 threads, 4x4 outputs each
    const int tx = t & 15;
    const int ty = t >> 4;

    float acc[4][4];
#pragma unroll
    for (int i = 0; i < 4; i++)
#pragma unroll
        for (int j = 0; j < 4; j++) acc[i][j] = 0.0f;

    const int arow = row0 + lr;       // may exceed N on last row-block
    const int wrow = col0 + lr;       // always < M (M is a multiple of 64)

    for (int kc = 0; kc < K; kc += KC) {
        float4 av = make_float4(0.f, 0.f, 0.f, 0.f);
        if (arow < N) {
            const float* Ap;
            if (kc < K0) Ap = A0 + (size_t)arow * K0 + kc;           // left half
            else         Ap = A1 + (size_t)arow * (K - K0) + (kc - K0); // right half
            av = *reinterpret_cast<const float4*>(Ap + lq * 4);
        }
        const float4 wv = *reinterpret_cast<const float4*>(
            W + (size_t)wrow * K + kc + lq * 4);

        __syncthreads();   // previous iteration's LDS reads must finish
        As[lq * 4 + 0][lr] = av.x;
        As[lq * 4 + 1][lr] = av.y;
        As[lq * 4 + 2][lr] = av.z;
        As[lq * 4 + 3][lr] = av.w;
        Ws[lq * 4 + 0][lr] = wv.x;
        Ws[lq * 4 + 1][lr] = wv.y;
        Ws[lq * 4 + 2][lr] = wv.z;
        Ws[lq * 4 + 3][lr] = wv.w;
        __syncthreads();

#pragma unroll
        for (int kk = 0; kk < KC; kk++) {
            const float4 a4 = *reinterpret_cast<const float4*>(&As[kk][ty * 4]);
            const float4 w4 = *reinterpret_cast<const float4*>(&Ws[kk][tx * 4]);
            const float ar[4] = {a4.x, a4.y, a4.z, a4.w};
            const float wr[4] = {w4.x, w4.y, w4.z, w4.w};
#pragma unroll
            for (int i = 0; i < 4; i++)
#pragma unroll
                for (int j = 0; j < 4; j++)
                    acc[i][j] = fmaf(ar[i], wr[j], acc[i][j]);
        }
    }

    const float4 b4 = *reinterpret_cast<const float4*>(bias + col0 + tx * 4);
    const float br[4] = {b4.x, b4.y, b4.z, b4.w};
#pragma unroll
    for (int i = 0; i < 4; i++) {
        const int row = row0 + ty * 4 + i;
        if (row < N) {
            float v[4];
#pragma unroll
            for (int j = 0; j < 4; j++) {
                float u = acc[i][j] + br[j];
                if (ACT == 1) u = fmaxf(u, 0.0f);
                if (ACT == 2) u = tanhf(u);
                v[j] = u;
            }
            *reinterpret_cast<float4*>(C + (size_t)row * M + col0 + tx * 4) =
                make_float4(v[0], v[1], v[2], v[3]);
        }
    }
}

// out[dst] += m[src] over E edges; one wave (64 lanes) per edge, one float4
// per lane (H=256). Atomic fp32 adds (device scope by default).
__global__ __launch_bounds__(256) void scatter_add_kernel(
    const float4* __restrict__ m4, const int* __restrict__ ei,
    float* __restrict__ out, const int E)
{
    const unsigned tid = blockIdx.x * 256u + threadIdx.x;
    const unsigned e = tid >> 6;
    const unsigned q = tid & 63u;
    if (e < (unsigned)E) {
        const int src = ei[e];
        const int dst = ei[(size_t)E + e];
        const float4 v = m4[(size_t)src * 64 + q];
        float* o = out + (size_t)dst * 256 + q * 4;
        atomicAdd(o + 0, v.x);
        atomicAdd(o + 1, v.y);
        atomicAdd(o + 2, v.z);
        atomicAdd(o + 3, v.w);
    }
}

extern "C" void kernel_launch(void* const* d_in, const int* in_sizes, int n_in,
                              void* d_out, int out_size, void* d_ws, size_t ws_size,
                              hipStream_t stream)
{
    const float* x      = (const float*)d_in[0];
    const int*   ei     = (const int*)d_in[1];   // [2][E] (src row, dst row)
    // d_in[2] = steps (always 1 in this benchmark)
    const float* enc_w1 = (const float*)d_in[3];
    const float* enc_b1 = (const float*)d_in[4];
    const float* enc_w2 = (const float*)d_in[5];
    const float* enc_b2 = (const float*)d_in[6];
    const float* msg_w  = (const float*)d_in[7];
    const float* msg_b  = (const float*)d_in[8];
    const float* dec_w1 = (const float*)d_in[9];
    const float* dec_b1 = (const float*)d_in[10];
    const float* dec_w2 = (const float*)d_in[11];
    const float* dec_b2 = (const float*)d_in[12];

    const int N = 50000, D = 128, H = 256;
    const int E = in_sizes[1] / 2;

    // Workspace slabs, each N*H floats (51.2 MB); 3 slabs with reuse.
    float* slabA = (float*)d_ws;                   // h1, then m, then d
    float* slabB = slabA + (size_t)N * H;          // h
    float* slabC = slabB + (size_t)N * H;          // aggr

    const dim3 blk(256);
    const dim3 gridH(H / TS, (N + TS - 1) / TS);   // M=256
    const dim3 gridD(D / TS, (N + TS - 1) / TS);   // M=128

    // 1) h1 = relu(x @ enc_w1^T + b1)   [N,128] -> [N,256]
    gemm_bias_act<1><<<gridH, blk, 0, stream>>>(x, x, D, D, enc_w1, enc_b1,
                                                slabA, N, H);
    // 2) h = relu(h1 @ enc_w2^T + b2)
    gemm_bias_act<1><<<gridH, blk, 0, stream>>>(slabA, slabA, H, H, enc_w2,
                                                enc_b2, slabB, N, H);
    // 3) m = h @ msg_w^T + msg_b        (no activation)
    gemm_bias_act<0><<<gridH, blk, 0, stream>>>(slabB, slabB, H, H, msg_w,
                                                msg_b, slabA, N, H);
    // 4) aggr = segment_sum(m[src], dst)
    hipMemsetAsync(slabC, 0, (size_t)N * H * sizeof(float), stream);
    {
        const long long total = (long long)E * 64;
        const int nblk = (int)((total + 255) / 256);
        scatter_add_kernel<<<dim3(nblk), blk, 0, stream>>>(
            (const float4*)slabA, ei, slabC, E);
    }
    // 5) d = relu(cat(aggr, h) @ dec_w1^T + b1)   K=512 split at 256
    gemm_bias_act<1><<<gridH, blk, 0, stream>>>(slabC, slabB, H, 2 * H, dec_w1,
                                                dec_b1, slabA, N, H);
    // 6) out = tanh(d @ dec_w2^T + b2)  [N,256] -> [N,128]
    gemm_bias_act<2><<<gridD, blk, 0, stream>>>(slabA, slabA, H, H, dec_w2,
                                                dec_b2, (float*)d_out, N, D);
}

// Round 2
// 766.053 us; speedup vs baseline: 2.4899x; 2.4899x over previous
//
#include <hip/hip_runtime.h>
#include <cmath>

// GNNCASimple: x:[N,128] -> enc MLP -> h:[N,256] -> msg GEMM -> m:[N,256]
// -> segment_sum over E edges -> aggr:[N,256] -> dec(cat(aggr,h)) -> out:[N,128]
// N=50000, E=400000, D=128, H=256, steps=1 (static).
//
// R2: replaced 102.4M-scalar-atomic scatter (1335 us, atomic-throughput-bound)
// with device-built CSR (histogram + scan + bucket-fill) + per-node gather-sum
// (register accumulation, one coalesced 1KB write/node, no output atomics).

#define TS 64
#define KC 16
#define LDSS 68   // padded leading dim (floats)

// C[N,M] = act(A[N,K] @ W[M,K]^T + bias), A = concat(A0 cols [0,K0), A1 rest).
// ACT: 0=none, 1=relu, 2=tanh.
template <int ACT>
__global__ __launch_bounds__(256) void gemm_bias_act(
    const float* __restrict__ A0, const float* __restrict__ A1,
    const int K0, const int K,
    const float* __restrict__ W, const float* __restrict__ bias,
    float* __restrict__ C, const int N, const int M)
{
    __shared__ float As[KC][LDSS];
    __shared__ float Ws[KC][LDSS];

    const int t    = threadIdx.x;
    const int col0 = blockIdx.x * TS;
    const int row0 = blockIdx.y * TS;

    const int lr = t >> 2;   // 0..63
    const int lq = t & 3;    // 0..3
    const int tx = t & 15;
    const int ty = t >> 4;

    float acc[4][4];
#pragma unroll
    for (int i = 0; i < 4; i++)
#pragma unroll
        for (int j = 0; j < 4; j++) acc[i][j] = 0.0f;

    const int arow = row0 + lr;
    const int wrow = col0 + lr;

    for (int kc = 0; kc < K; kc += KC) {
        float4 av = make_float4(0.f, 0.f, 0.f, 0.f);
        if (arow < N) {
            const float* Ap;
            if (kc < K0) Ap = A0 + (size_t)arow * K0 + kc;
            else         Ap = A1 + (size_t)arow * (K - K0) + (kc - K0);
            av = *reinterpret_cast<const float4*>(Ap + lq * 4);
        }
        const float4 wv = *reinterpret_cast<const float4*>(
            W + (size_t)wrow * K + kc + lq * 4);

        __syncthreads();
        As[lq * 4 + 0][lr] = av.x;
        As[lq * 4 + 1][lr] = av.y;
        As[lq * 4 + 2][lr] = av.z;
        As[lq * 4 + 3][lr] = av.w;
        Ws[lq * 4 + 0][lr] = wv.x;
        Ws[lq * 4 + 1][lr] = wv.y;
        Ws[lq * 4 + 2][lr] = wv.z;
        Ws[lq * 4 + 3][lr] = wv.w;
        __syncthreads();

#pragma unroll
        for (int kk = 0; kk < KC; kk++) {
            const float4 a4 = *reinterpret_cast<const float4*>(&As[kk][ty * 4]);
            const float4 w4 = *reinterpret_cast<const float4*>(&Ws[kk][tx * 4]);
            const float ar[4] = {a4.x, a4.y, a4.z, a4.w};
            const float wr[4] = {w4.x, w4.y, w4.z, w4.w};
#pragma unroll
            for (int i = 0; i < 4; i++)
#pragma unroll
                for (int j = 0; j < 4; j++)
                    acc[i][j] = fmaf(ar[i], wr[j], acc[i][j]);
        }
    }

    const float4 b4 = *reinterpret_cast<const float4*>(bias + col0 + tx * 4);
    const float br[4] = {b4.x, b4.y, b4.z, b4.w};
#pragma unroll
    for (int i = 0; i < 4; i++) {
        const int row = row0 + ty * 4 + i;
        if (row < N) {
            float v[4];
#pragma unroll
            for (int j = 0; j < 4; j++) {
                float u = acc[i][j] + br[j];
                if (ACT == 1) u = fmaxf(u, 0.0f);
                if (ACT == 2) u = tanhf(u);
                v[j] = u;
            }
            *reinterpret_cast<float4*>(C + (size_t)row * M + col0 + tx * 4) =
                make_float4(v[0], v[1], v[2], v[3]);
        }
    }
}

// ---- CSR build ----

__global__ __launch_bounds__(256) void histo_kernel(
    const int* __restrict__ ei, int* __restrict__ deg, const int E)
{
    const int e = blockIdx.x * 256 + threadIdx.x;
    if (e < E) atomicAdd(&deg[ei[(size_t)E + e]], 1);
}

// Single-block exclusive scan over deg[0..Nn) -> offsets[0..Nn], cursor copy.
__global__ __launch_bounds__(256) void scan_kernel(
    const int* __restrict__ deg, int* __restrict__ offsets,
    int* __restrict__ cursor, const int Nn)
{
    __shared__ int partials[256];
    const int t = threadIdx.x;
    const int chunk = (Nn + 255) / 256;
    const int lo = t * chunk;
    const int hi = min(lo + chunk, Nn);
    int s = 0;
    for (int i = lo; i < hi; i++) s += deg[i];
    partials[t] = s;
    __syncthreads();
    // Hillis-Steele inclusive scan
    for (int d = 1; d < 256; d <<= 1) {
        int v = (t >= d) ? partials[t - d] : 0;
        __syncthreads();
        partials[t] += v;
        __syncthreads();
    }
    int run = (t == 0) ? 0 : partials[t - 1];
    for (int i = lo; i < hi; i++) {
        offsets[i] = run;
        cursor[i]  = run;
        run += deg[i];
    }
    if (t == 255) offsets[Nn] = run;   // == E
}

__global__ __launch_bounds__(256) void fill_kernel(
    const int* __restrict__ ei, int* __restrict__ cursor,
    int* __restrict__ bucket, const int E)
{
    const int e = blockIdx.x * 256 + threadIdx.x;
    if (e < E) {
        const int src = ei[e];
        const int dst = ei[(size_t)E + e];
        const int pos = atomicAdd(&cursor[dst], 1);
        bucket[pos] = src;
    }
}

// One wave per destination node; 64 lanes x float4 = 256 floats.
__global__ __launch_bounds__(256) void gather_sum_kernel(
    const float4* __restrict__ m4, const int* __restrict__ bucket,
    const int* __restrict__ offsets, float4* __restrict__ out, const int Nn)
{
    const int wave = (int)((blockIdx.x * 256u + threadIdx.x) >> 6);
    const int lane = threadIdx.x & 63;
    if (wave >= Nn) return;
    const int beg = offsets[wave];
    const int end = offsets[wave + 1];
    float4 acc = make_float4(0.f, 0.f, 0.f, 0.f);
    int e = beg;
    for (; e + 1 < end; e += 2) {
        const int s0 = bucket[e];
        const int s1 = bucket[e + 1];
        const float4 v0 = m4[(size_t)s0 * 64 + lane];
        const float4 v1 = m4[(size_t)s1 * 64 + lane];
        acc.x += v0.x + v1.x;
        acc.y += v0.y + v1.y;
        acc.z += v0.z + v1.z;
        acc.w += v0.w + v1.w;
    }
    if (e < end) {
        const float4 v0 = m4[(size_t)bucket[e] * 64 + lane];
        acc.x += v0.x; acc.y += v0.y; acc.z += v0.z; acc.w += v0.w;
    }
    out[(size_t)wave * 64 + lane] = acc;
}

extern "C" void kernel_launch(void* const* d_in, const int* in_sizes, int n_in,
                              void* d_out, int out_size, void* d_ws, size_t ws_size,
                              hipStream_t stream)
{
    const float* x      = (const float*)d_in[0];
    const int*   ei     = (const int*)d_in[1];   // [2][E]
    const float* enc_w1 = (const float*)d_in[3];
    const float* enc_b1 = (const float*)d_in[4];
    const float* enc_w2 = (const float*)d_in[5];
    const float* enc_b2 = (const float*)d_in[6];
    const float* msg_w  = (const float*)d_in[7];
    const float* msg_b  = (const float*)d_in[8];
    const float* dec_w1 = (const float*)d_in[9];
    const float* dec_b1 = (const float*)d_in[10];
    const float* dec_w2 = (const float*)d_in[11];
    const float* dec_b2 = (const float*)d_in[12];

    const int N = 50000, D = 128, H = 256;
    const int E = in_sizes[1] / 2;

    // Workspace slabs, each N*H floats (51.2 MB): proven ws budget from R1.
    float* slabA = (float*)d_ws;                   // h1 -> m -> d
    float* slabB = slabA + (size_t)N * H;          // h
    float* slabC = slabB + (size_t)N * H;          // aggr

    // CSR scratch lives in d_out (N*D floats = 25.6 MB, fully overwritten by
    // the final GEMM after the CSR arrays are dead).
    int* deg     = (int*)d_out;                    // [N]
    int* offsets = deg + N;                        // [N+1]
    int* cursor  = offsets + N + 1;                // [N]
    int* bucket  = cursor + N;                     // [E]

    const dim3 blk(256);
    const dim3 gridH(H / TS, (N + TS - 1) / TS);
    const dim3 gridD(D / TS, (N + TS - 1) / TS);
    const int eblk = (E + 255) / 256;

    // 1) h1 = relu(x @ enc_w1^T + b1)
    gemm_bias_act<1><<<gridH, blk, 0, stream>>>(x, x, D, D, enc_w1, enc_b1,
                                                slabA, N, H);
    // CSR build overlaps conceptually; runs before gather is needed.
    hipMemsetAsync(deg, 0, (size_t)N * sizeof(int), stream);
    histo_kernel<<<dim3(eblk), blk, 0, stream>>>(ei, deg, E);
    scan_kernel<<<dim3(1), blk, 0, stream>>>(deg, offsets, cursor, N);
    fill_kernel<<<dim3(eblk), blk, 0, stream>>>(ei, cursor, bucket, E);

    // 2) h = relu(h1 @ enc_w2^T + b2)
    gemm_bias_act<1><<<gridH, blk, 0, stream>>>(slabA, slabA, H, H, enc_w2,
                                                enc_b2, slabB, N, H);
    // 3) m = h @ msg_w^T + msg_b
    gemm_bias_act<0><<<gridH, blk, 0, stream>>>(slabB, slabB, H, H, msg_w,
                                                msg_b, slabA, N, H);
    // 4) aggr = segment_sum(m[src], dst) via CSR gather (no atomics)
    {
        const int nwaves = N;
        const int nblk = (nwaves * 64 + 255) / 256;
        gather_sum_kernel<<<dim3(nblk), blk, 0, stream>>>(
            (const float4*)slabA, bucket, offsets, (float4*)slabC, N);
    }
    // 5) d = relu(cat(aggr, h) @ dec_w1^T + b1)   K=512 split at 256
    gemm_bias_act<1><<<gridH, blk, 0, stream>>>(slabC, slabB, H, 2 * H, dec_w1,
                                                dec_b1, slabA, N, H);
    // 6) out = tanh(d @ dec_w2^T + b2)  (overwrites the CSR scratch in d_out)
    gemm_bias_act<2><<<gridD, blk, 0, stream>>>(slabA, slabA, H, H, dec_w2,
                                                dec_b2, (float*)d_out, N, D);
}

// Round 3
// 531.670 us; speedup vs baseline: 3.5875x; 1.4408x over previous
//
#include <hip/hip_runtime.h>
#include <cmath>

// GNNCASimple: x:[N,128] -> enc MLP -> h:[N,256] -> msg GEMM -> m:[N,256]
// -> segment_sum over E edges -> aggr:[N,256] -> dec(cat(aggr,h)) -> out:[N,128]
// N=50000, E=400000, D=128, H=256, steps=1.
//
// R2: CSR gather replaced atomic scatter (1907 -> 766 us).
// R3: bf16 MFMA GEMMs (16x16x32), bf16 activation storage. fp32 GEMMs were
//     ~560 us at ~34-58 TF vector; MFMA path targets ~100-150 us total GEMM.

typedef __attribute__((ext_vector_type(8))) short  short8;   // 8 bf16 (4 VGPR)
typedef __attribute__((ext_vector_type(4))) float  f32x4;    // MFMA acc
typedef __attribute__((ext_vector_type(4))) unsigned short us4;

typedef unsigned short u16;
typedef unsigned int   u32;

static __device__ __forceinline__ u16 f2bf(float f) {
    u32 u = __float_as_uint(f);
    u = (u + 0x7FFFu + ((u >> 16) & 1u)) >> 16;   // round-to-nearest-even
    return (u16)u;
}
static __device__ __forceinline__ float bf2f(u16 h) {
    return __uint_as_float(((u32)h) << 16);
}

// ---------------- bf16 MFMA GEMM ----------------
// C[N,M] = act(A[N,K] @ W[M,K]^T + bias). A = concat(A0 cols [0,K0), A1 rest),
// both bf16. W bf16 [M,K]. bias fp32. ACT: 0=none 1=relu 2=tanh.
// Tile 128x128, BK=32, 256 threads (4 waves, each 64x64 = 4x4 MFMA tiles).
#define ASTRIDE 40   // bf16 elems per LDS row (80 B): 2-way banks, 16B aligned

template <int ACT, bool OUT_BF16>
__global__ __launch_bounds__(256) void gemm_bf16(
    const u16* __restrict__ A0, const u16* __restrict__ A1,
    const int K0, const int K,
    const u16* __restrict__ W, const float* __restrict__ bias,
    void* __restrict__ Cout, const int N, const int M)
{
    __shared__ u16 As[128 * ASTRIDE];
    __shared__ u16 Ws[128 * ASTRIDE];

    const int t    = threadIdx.x;
    const int c0   = blockIdx.x * 128;
    const int r0   = blockIdx.y * 128;
    const int wave = t >> 6;
    const int lane = t & 63;
    const int n    = lane & 15;       // fragment row index
    const int q    = lane >> 4;       // k-granule / acc row-quad
    const int wr   = (wave & 1) * 64; // wave's row offset in tile
    const int wc   = (wave >> 1) * 64;

    // staging map: granule id = t + i*256 -> row = id>>2 (0..127), c8 = id&3
    const int srow = t >> 2;
    const int sc8  = t & 3;

    f32x4 acc[4][4];
#pragma unroll
    for (int i = 0; i < 4; i++)
#pragma unroll
        for (int j = 0; j < 4; j++) acc[i][j] = (f32x4)0.0f;

    const int KA1 = K - K0;

    for (int kc = 0; kc < K; kc += 32) {
        // ---- global loads (2 granules of A, 2 of W per thread) ----
        uint4 va[2], vb[2];
#pragma unroll
        for (int i = 0; i < 2; i++) {
            const int row  = srow + i * 64;        // id>>2 with id = t + 256i
            const int arow = min(r0 + row, N - 1); // clamp tail rows (junk OK)
            const int col  = kc + sc8 * 8;
            const u16* ap = (col < K0)
                ? A0 + (size_t)arow * K0 + col
                : A1 + (size_t)arow * KA1 + (col - K0);
            va[i] = *reinterpret_cast<const uint4*>(ap);
            const int wrow = c0 + row;             // M is a multiple of 128
            vb[i] = *reinterpret_cast<const uint4*>(
                W + (size_t)wrow * K + col);
        }
        __syncthreads();   // previous iter's LDS reads done
#pragma unroll
        for (int i = 0; i < 2; i++) {
            const int row = srow + i * 64;
            *reinterpret_cast<uint4*>(&As[row * ASTRIDE + sc8 * 8]) = va[i];
            *reinterpret_cast<uint4*>(&Ws[row * ASTRIDE + sc8 * 8]) = vb[i];
        }
        __syncthreads();

        // ---- fragments + MFMA ----
        short8 af[4], bf[4];
#pragma unroll
        for (int i = 0; i < 4; i++)
            af[i] = *reinterpret_cast<const short8*>(
                &As[(wr + i * 16 + n) * ASTRIDE + q * 8]);
#pragma unroll
        for (int j = 0; j < 4; j++)
            bf[j] = *reinterpret_cast<const short8*>(
                &Ws[(wc + j * 16 + n) * ASTRIDE + q * 8]);
#pragma unroll
        for (int i = 0; i < 4; i++)
#pragma unroll
            for (int j = 0; j < 4; j++)
                acc[i][j] = __builtin_amdgcn_mfma_f32_16x16x32_bf16(
                    af[i], bf[j], acc[i][j], 0, 0, 0);
    }

    // ---- epilogue: C row = r0+wr+i*16+q*4+reg, col = c0+wc+j*16+n ----
    float bv[4];
#pragma unroll
    for (int j = 0; j < 4; j++) bv[j] = bias[c0 + wc + j * 16 + n];

#pragma unroll
    for (int i = 0; i < 4; i++) {
        const int rbase = r0 + wr + i * 16 + q * 4;
#pragma unroll
        for (int reg = 0; reg < 4; reg++) {
            const int row = rbase + reg;
            if (row < N) {
#pragma unroll
                for (int j = 0; j < 4; j++) {
                    const int col = c0 + wc + j * 16 + n;
                    float v = acc[i][j][reg] + bv[j];
                    if (ACT == 1) v = fmaxf(v, 0.0f);
                    if (ACT == 2) v = tanhf(v);
                    if (OUT_BF16)
                        ((u16*)Cout)[(size_t)row * M + col] = f2bf(v);
                    else
                        ((float*)Cout)[(size_t)row * M + col] = v;
                }
            }
        }
    }
}

// ---------------- converts ----------------
__global__ __launch_bounds__(256) void cvt_kernel(
    const float* __restrict__ s, u16* __restrict__ d, const int n4)
{
    const int i = blockIdx.x * 256 + threadIdx.x;
    if (i < n4) {
        const float4 v = reinterpret_cast<const float4*>(s)[i];
        us4 o = { f2bf(v.x), f2bf(v.y), f2bf(v.z), f2bf(v.w) };
        reinterpret_cast<us4*>(d)[i] = o;
    }
}

__global__ __launch_bounds__(256) void cvt5_kernel(
    const float* s0, const float* s1, const float* s2, const float* s3,
    const float* s4, u16* d0, u16* d1, u16* d2, u16* d3, u16* d4,
    int n0, int n1, int n2, int n3, int n4)
{
    const float* s; u16* d; int n4c;
    switch (blockIdx.y) {
        case 0: s = s0; d = d0; n4c = n0; break;
        case 1: s = s1; d = d1; n4c = n1; break;
        case 2: s = s2; d = d2; n4c = n2; break;
        case 3: s = s3; d = d3; n4c = n3; break;
        default: s = s4; d = d4; n4c = n4; break;
    }
    const int i = blockIdx.x * 256 + threadIdx.x;
    if (i < n4c) {
        const float4 v = reinterpret_cast<const float4*>(s)[i];
        us4 o = { f2bf(v.x), f2bf(v.y), f2bf(v.z), f2bf(v.w) };
        reinterpret_cast<us4*>(d)[i] = o;
    }
}

// ---------------- CSR build ----------------
__global__ __launch_bounds__(256) void histo_kernel(
    const int* __restrict__ ei, int* __restrict__ deg, const int E)
{
    const int e = blockIdx.x * 256 + threadIdx.x;
    if (e < E) atomicAdd(&deg[ei[(size_t)E + e]], 1);
}

__global__ __launch_bounds__(256) void scan_kernel(
    const int* __restrict__ deg, int* __restrict__ offsets,
    int* __restrict__ cursor, const int Nn)
{
    __shared__ int partials[256];
    const int t = threadIdx.x;
    const int chunk = (Nn + 255) / 256;
    const int lo = t * chunk;
    const int hi = min(lo + chunk, Nn);
    int s = 0;
    for (int i = lo; i < hi; i++) s += deg[i];
    partials[t] = s;
    __syncthreads();
    for (int d = 1; d < 256; d <<= 1) {
        int v = (t >= d) ? partials[t - d] : 0;
        __syncthreads();
        partials[t] += v;
        __syncthreads();
    }
    int run = (t == 0) ? 0 : partials[t - 1];
    for (int i = lo; i < hi; i++) {
        offsets[i] = run;
        cursor[i]  = run;
        run += deg[i];
    }
    if (t == 255) offsets[Nn] = run;   // == E
}

__global__ __launch_bounds__(256) void fill_kernel(
    const int* __restrict__ ei, int* __restrict__ cursor,
    int* __restrict__ bucket, const int E)
{
    const int e = blockIdx.x * 256 + threadIdx.x;
    if (e < E) {
        const int src = ei[e];
        const int dst = ei[(size_t)E + e];
        const int pos = atomicAdd(&cursor[dst], 1);
        bucket[pos] = src;
    }
}

// ---------------- gather-sum (bf16 m -> bf16 aggr) ----------------
// One wave per destination node; 64 lanes x 4 bf16 = 256 cols.
__global__ __launch_bounds__(256) void gather_sum_kernel(
    const u16* __restrict__ m, const int* __restrict__ bucket,
    const int* __restrict__ offsets, u16* __restrict__ out, const int Nn)
{
    const int wave = (int)((blockIdx.x * 256u + threadIdx.x) >> 6);
    const int lane = threadIdx.x & 63;
    if (wave >= Nn) return;
    const int beg = offsets[wave];
    const int end = offsets[wave + 1];
    float a0 = 0.f, a1 = 0.f, a2 = 0.f, a3 = 0.f;
    int e = beg;
    for (; e + 1 < end; e += 2) {
        const int s0 = bucket[e];
        const int s1 = bucket[e + 1];
        const us4 v0 = *reinterpret_cast<const us4*>(&m[(size_t)s0 * 256 + lane * 4]);
        const us4 v1 = *reinterpret_cast<const us4*>(&m[(size_t)s1 * 256 + lane * 4]);
        a0 += bf2f(v0.x) + bf2f(v1.x);
        a1 += bf2f(v0.y) + bf2f(v1.y);
        a2 += bf2f(v0.z) + bf2f(v1.z);
        a3 += bf2f(v0.w) + bf2f(v1.w);
    }
    if (e < end) {
        const us4 v0 = *reinterpret_cast<const us4*>(
            &m[(size_t)bucket[e] * 256 + lane * 4]);
        a0 += bf2f(v0.x); a1 += bf2f(v0.y); a2 += bf2f(v0.z); a3 += bf2f(v0.w);
    }
    us4 o = { f2bf(a0), f2bf(a1), f2bf(a2), f2bf(a3) };
    *reinterpret_cast<us4*>(&out[(size_t)wave * 256 + lane * 4]) = o;
}

extern "C" void kernel_launch(void* const* d_in, const int* in_sizes, int n_in,
                              void* d_out, int out_size, void* d_ws, size_t ws_size,
                              hipStream_t stream)
{
    const float* x      = (const float*)d_in[0];
    const int*   ei     = (const int*)d_in[1];   // [2][E]
    const float* enc_w1 = (const float*)d_in[3];
    const float* enc_b1 = (const float*)d_in[4];
    const float* enc_w2 = (const float*)d_in[5];
    const float* enc_b2 = (const float*)d_in[6];
    const float* msg_w  = (const float*)d_in[7];
    const float* msg_b  = (const float*)d_in[8];
    const float* dec_w1 = (const float*)d_in[9];
    const float* dec_b1 = (const float*)d_in[10];
    const float* dec_w2 = (const float*)d_in[11];
    const float* dec_b2 = (const float*)d_in[12];

    const int N = 50000, D = 128, H = 256;
    const int E = in_sizes[1] / 2;

    // ws layout (ushort), total ~141.5 MB (R1 proved >= 153.6 MB available)
    u16* xb   = (u16*)d_ws;                 // [N,128]
    u16* h1   = xb   + (size_t)N * D;       // [N,256]
    u16* h    = h1   + (size_t)N * H;
    u16* m    = h    + (size_t)N * H;
    u16* aggr = m    + (size_t)N * H;
    u16* dbuf = aggr + (size_t)N * H;
    u16* wb   = dbuf + (size_t)N * H;       // bf16 weights
    u16* w_enc1 = wb;                       // 256*128
    u16* w_enc2 = w_enc1 + 256 * 128;       // 256*256
    u16* w_msg  = w_enc2 + 256 * 256;       // 256*256
    u16* w_dec1 = w_msg  + 256 * 256;       // 256*512
    u16* w_dec2 = w_dec1 + 256 * 512;       // 128*256

    // CSR scratch in d_out (dead before final GEMM overwrites it)
    int* deg     = (int*)d_out;             // [N]
    int* offsets = deg + N;                 // [N+1]
    int* cursor  = offsets + N + 1;         // [N]
    int* bucket  = cursor + N;              // [E]

    const dim3 blk(256);
    const dim3 gridH(2, (N + 127) / 128);   // M=256
    const dim3 gridD(1, (N + 127) / 128);   // M=128
    const int eblk = (E + 255) / 256;

    // converts
    cvt_kernel<<<dim3((N * D / 4 + 255) / 256), blk, 0, stream>>>(x, xb, N * D / 4);
    cvt5_kernel<<<dim3((256 * 512 / 4 + 255) / 256, 5), blk, 0, stream>>>(
        enc_w1, enc_w2, msg_w, dec_w1, dec_w2,
        w_enc1, w_enc2, w_msg, w_dec1, w_dec2,
        256 * 128 / 4, 256 * 256 / 4, 256 * 256 / 4, 256 * 512 / 4, 128 * 256 / 4);

    // CSR build
    hipMemsetAsync(deg, 0, (size_t)N * sizeof(int), stream);
    histo_kernel<<<dim3(eblk), blk, 0, stream>>>(ei, deg, E);
    scan_kernel<<<dim3(1), blk, 0, stream>>>(deg, offsets, cursor, N);
    fill_kernel<<<dim3(eblk), blk, 0, stream>>>(ei, cursor, bucket, E);

    // 1) h1 = relu(x @ enc_w1^T + b1)
    gemm_bf16<1, true><<<gridH, blk, 0, stream>>>(xb, xb, D, D, w_enc1, enc_b1,
                                                  h1, N, H);
    // 2) h = relu(h1 @ enc_w2^T + b2)
    gemm_bf16<1, true><<<gridH, blk, 0, stream>>>(h1, h1, H, H, w_enc2, enc_b2,
                                                  h, N, H);
    // 3) m = h @ msg_w^T + msg_b
    gemm_bf16<0, true><<<gridH, blk, 0, stream>>>(h, h, H, H, w_msg, msg_b,
                                                  m, N, H);
    // 4) aggr = segment_sum(m[src], dst)
    gather_sum_kernel<<<dim3((N * 64 + 255) / 256), blk, 0, stream>>>(
        m, bucket, offsets, aggr, N);
    // 5) d = relu(cat(aggr, h) @ dec_w1^T + b1), K=512 split at 256
    gemm_bf16<1, true><<<gridH, blk, 0, stream>>>(aggr, h, H, 2 * H, w_dec1,
                                                  dec_b1, dbuf, N, H);
    // 6) out = tanh(d @ dec_w2^T + b2), fp32 out (overwrites CSR scratch)
    gemm_bf16<2, false><<<gridD, blk, 0, stream>>>(dbuf, dbuf, H, H, w_dec2,
                                                   dec_b2, (float*)d_out, N, D);
}

// Round 5
// 425.166 us; speedup vs baseline: 4.4862x; 1.2505x over previous
//
#include <hip/hip_runtime.h>
#include <cmath>

// GNNCASimple: x:[N,128] -> enc MLP -> h:[N,256] -> msg GEMM -> m:[N,256]
// -> segment_sum over E edges -> aggr:[N,256] -> dec(cat(aggr,h)) -> out:[N,128]
// N=50000, E=400000, D=128, H=256, steps=1.
//
// R2: CSR gather replaced atomic scatter (1907 -> 766 us).
// R3: bf16 MFMA GEMMs + bf16 activations (766 -> 532 us).
// R4: hierarchical scan (scan was 121 us on 1 CU) -- but replays diverged:
//     CSR scratch lived in d_out, which the harness zeroes for the
//     correctness launch and poisons 0xAA for timed launches; poison-derived
//     negative indices -> wild reads (slow + tanh-saturated outputs).
// R5: CSR scratch moved fully into d_ws; memset node -> zero kernel;
//     out-of-place block-sums scan; defensive index clamps in fill/gather.
//     d_out is written exactly once (final GEMM).

typedef __attribute__((ext_vector_type(8))) short  short8;   // 8 bf16 (4 VGPR)
typedef __attribute__((ext_vector_type(4))) float  f32x4;    // MFMA acc
typedef __attribute__((ext_vector_type(4))) unsigned short us4;

typedef unsigned short u16;
typedef unsigned int   u32;

static __device__ __forceinline__ u16 f2bf(float f) {
    u32 u = __float_as_uint(f);
    u = (u + 0x7FFFu + ((u >> 16) & 1u)) >> 16;   // round-to-nearest-even
    return (u16)u;
}
static __device__ __forceinline__ float bf2f(u16 h) {
    return __uint_as_float(((u32)h) << 16);
}

// ---------------- bf16 MFMA GEMM ----------------
// C[N,M] = act(A[N,K] @ W[M,K]^T + bias). A = concat(A0 cols [0,K0), A1 rest),
// both bf16. W bf16 [M,K]. bias fp32. ACT: 0=none 1=relu 2=tanh.
// Tile 128x128, BK=32, 256 threads (4 waves, each 64x64 = 4x4 MFMA tiles).
#define ASTRIDE 40   // bf16 elems per LDS row (80 B): 2-way banks, 16B aligned

template <int ACT, bool OUT_BF16>
__global__ __launch_bounds__(256) void gemm_bf16(
    const u16* __restrict__ A0, const u16* __restrict__ A1,
    const int K0, const int K,
    const u16* __restrict__ W, const float* __restrict__ bias,
    void* __restrict__ Cout, const int N, const int M)
{
    __shared__ u16 As[128 * ASTRIDE];
    __shared__ u16 Ws[128 * ASTRIDE];

    const int t    = threadIdx.x;
    const int c0   = blockIdx.x * 128;
    const int r0   = blockIdx.y * 128;
    const int wave = t >> 6;
    const int lane = t & 63;
    const int n    = lane & 15;       // fragment row index
    const int q    = lane >> 4;       // k-granule / acc row-quad
    const int wr   = (wave & 1) * 64;
    const int wc   = (wave >> 1) * 64;

    const int srow = t >> 2;
    const int sc8  = t & 3;

    f32x4 acc[4][4];
#pragma unroll
    for (int i = 0; i < 4; i++)
#pragma unroll
        for (int j = 0; j < 4; j++) acc[i][j] = (f32x4)0.0f;

    const int KA1 = K - K0;

    for (int kc = 0; kc < K; kc += 32) {
        uint4 va[2], vb[2];
#pragma unroll
        for (int i = 0; i < 2; i++) {
            const int row  = srow + i * 64;
            const int arow = min(r0 + row, N - 1); // clamp tail rows (junk OK)
            const int col  = kc + sc8 * 8;
            const u16* ap = (col < K0)
                ? A0 + (size_t)arow * K0 + col
                : A1 + (size_t)arow * KA1 + (col - K0);
            va[i] = *reinterpret_cast<const uint4*>(ap);
            const int wrow = c0 + row;             // M is a multiple of 128
            vb[i] = *reinterpret_cast<const uint4*>(
                W + (size_t)wrow * K + col);
        }
        __syncthreads();
#pragma unroll
        for (int i = 0; i < 2; i++) {
            const int row = srow + i * 64;
            *reinterpret_cast<uint4*>(&As[row * ASTRIDE + sc8 * 8]) = va[i];
            *reinterpret_cast<uint4*>(&Ws[row * ASTRIDE + sc8 * 8]) = vb[i];
        }
        __syncthreads();

        short8 af[4], bf[4];
#pragma unroll
        for (int i = 0; i < 4; i++)
            af[i] = *reinterpret_cast<const short8*>(
                &As[(wr + i * 16 + n) * ASTRIDE + q * 8]);
#pragma unroll
        for (int j = 0; j < 4; j++)
            bf[j] = *reinterpret_cast<const short8*>(
                &Ws[(wc + j * 16 + n) * ASTRIDE + q * 8]);
#pragma unroll
        for (int i = 0; i < 4; i++)
#pragma unroll
            for (int j = 0; j < 4; j++)
                acc[i][j] = __builtin_amdgcn_mfma_f32_16x16x32_bf16(
                    af[i], bf[j], acc[i][j], 0, 0, 0);
    }

    float bv[4];
#pragma unroll
    for (int j = 0; j < 4; j++) bv[j] = bias[c0 + wc + j * 16 + n];

#pragma unroll
    for (int i = 0; i < 4; i++) {
        const int rbase = r0 + wr + i * 16 + q * 4;
#pragma unroll
        for (int reg = 0; reg < 4; reg++) {
            const int row = rbase + reg;
            if (row < N) {
#pragma unroll
                for (int j = 0; j < 4; j++) {
                    const int col = c0 + wc + j * 16 + n;
                    float v = acc[i][j][reg] + bv[j];
                    if (ACT == 1) v = fmaxf(v, 0.0f);
                    if (ACT == 2) v = tanhf(v);
                    if (OUT_BF16)
                        ((u16*)Cout)[(size_t)row * M + col] = f2bf(v);
                    else
                        ((float*)Cout)[(size_t)row * M + col] = v;
                }
            }
        }
    }
}

// ---------------- converts ----------------
__global__ __launch_bounds__(256) void cvt_kernel(
    const float* __restrict__ s, u16* __restrict__ d, const int n4)
{
    const int i = blockIdx.x * 256 + threadIdx.x;
    if (i < n4) {
        const float4 v = reinterpret_cast<const float4*>(s)[i];
        us4 o = { f2bf(v.x), f2bf(v.y), f2bf(v.z), f2bf(v.w) };
        reinterpret_cast<us4*>(d)[i] = o;
    }
}

__global__ __launch_bounds__(256) void cvt5_kernel(
    const float* s0, const float* s1, const float* s2, const float* s3,
    const float* s4, u16* d0, u16* d1, u16* d2, u16* d3, u16* d4,
    int n0, int n1, int n2, int n3, int n4)
{
    const float* s; u16* d; int n4c;
    switch (blockIdx.y) {
        case 0: s = s0; d = d0; n4c = n0; break;
        case 1: s = s1; d = d1; n4c = n1; break;
        case 2: s = s2; d = d2; n4c = n2; break;
        case 3: s = s3; d = d3; n4c = n3; break;
        default: s = s4; d = d4; n4c = n4; break;
    }
    const int i = blockIdx.x * 256 + threadIdx.x;
    if (i < n4c) {
        const float4 v = reinterpret_cast<const float4*>(s)[i];
        us4 o = { f2bf(v.x), f2bf(v.y), f2bf(v.z), f2bf(v.w) };
        reinterpret_cast<us4*>(d)[i] = o;
    }
}

// ---------------- CSR build (all scratch in d_ws) ----------------
__global__ __launch_bounds__(256) void zero_kernel(
    int* __restrict__ p, const int n)
{
    const int i = blockIdx.x * 256 + threadIdx.x;
    if (i < n) p[i] = 0;
}

__global__ __launch_bounds__(256) void histo_kernel(
    const int* __restrict__ ei, int* __restrict__ deg, const int E,
    const int Nn)
{
    const int e = blockIdx.x * 256 + threadIdx.x;
    if (e < E) {
        const int dst = ei[(size_t)E + e];
        if ((unsigned)dst < (unsigned)Nn) atomicAdd(&deg[dst], 1);
    }
}

// 196 blocks: per-block sums of deg.
__global__ __launch_bounds__(256) void scan_reduce_kernel(
    const int* __restrict__ deg, int* __restrict__ bsums, const int Nn)
{
    __shared__ int s[256];
    const int t = threadIdx.x;
    const int i = blockIdx.x * 256 + t;
    s[t] = (i < Nn) ? deg[i] : 0;
    __syncthreads();
    for (int d = 128; d > 0; d >>= 1) {
        if (t < d) s[t] += s[t + d];
        __syncthreads();
    }
    if (t == 0) bsums[blockIdx.x] = s[0];
}

// Single block: exclusive scan of bsums[nb] -> bscan[nb] (out-of-place).
__global__ __launch_bounds__(256) void scan_sums_kernel(
    const int* __restrict__ bsums, int* __restrict__ bscan, const int nb)
{
    __shared__ int s[256];
    const int t = threadIdx.x;
    const int v = (t < nb) ? bsums[t] : 0;
    s[t] = v;
    __syncthreads();
    for (int d = 1; d < 256; d <<= 1) {
        int u = (t >= d) ? s[t - d] : 0;
        __syncthreads();
        s[t] += u;
        __syncthreads();
    }
    if (t < nb) bscan[t] = s[t] - v;   // exclusive
}

// Per-block exclusive scan + block offset -> offsets & cursor.
__global__ __launch_bounds__(256) void scan_final_kernel(
    const int* __restrict__ deg, const int* __restrict__ bscan,
    int* __restrict__ offsets, int* __restrict__ cursor, const int Nn)
{
    __shared__ int s[256];
    const int t = threadIdx.x;
    const int i = blockIdx.x * 256 + t;
    const int v = (i < Nn) ? deg[i] : 0;
    s[t] = v;
    __syncthreads();
    for (int d = 1; d < 256; d <<= 1) {
        int u = (t >= d) ? s[t - d] : 0;
        __syncthreads();
        s[t] += u;
        __syncthreads();
    }
    const int excl = s[t] - v + bscan[blockIdx.x];
    if (i < Nn) {
        offsets[i] = excl;
        cursor[i]  = excl;
        if (i == Nn - 1) offsets[Nn] = excl + v;   // == E
    }
}

__global__ __launch_bounds__(256) void fill_kernel(
    const int* __restrict__ ei, int* __restrict__ cursor,
    int* __restrict__ bucket, const int E, const int Nn)
{
    const int e = blockIdx.x * 256 + threadIdx.x;
    if (e < E) {
        const int src = ei[e];
        const int dst = ei[(size_t)E + e];
        if ((unsigned)dst < (unsigned)Nn) {
            const int pos = atomicAdd(&cursor[dst], 1);
            if ((unsigned)pos < (unsigned)E) bucket[pos] = src;
        }
    }
}

// ---------------- gather-sum (bf16 m -> bf16 aggr) ----------------
// One wave per destination node; 64 lanes x 4 bf16 = 256 cols.
// Index clamps: an out-of-range bucket/offset entry is skipped, never read.
__global__ __launch_bounds__(256) void gather_sum_kernel(
    const u16* __restrict__ m, const int* __restrict__ bucket,
    const int* __restrict__ offsets, u16* __restrict__ out,
    const int Nn, const int E)
{
    const int wave = (int)((blockIdx.x * 256u + threadIdx.x) >> 6);
    const int lane = threadIdx.x & 63;
    if (wave >= Nn) return;
    int beg = offsets[wave];
    int end = offsets[wave + 1];
    beg = max(0, min(beg, E));
    end = max(beg, min(end, E));
    float a0 = 0.f, a1 = 0.f, a2 = 0.f, a3 = 0.f;
    int e = beg;
    for (; e + 1 < end; e += 2) {
        const int s0 = bucket[e];
        const int s1 = bucket[e + 1];
        const bool ok0 = (unsigned)s0 < (unsigned)Nn;
        const bool ok1 = (unsigned)s1 < (unsigned)Nn;
        if (ok0) {
            const us4 v0 = *reinterpret_cast<const us4*>(
                &m[(size_t)s0 * 256 + lane * 4]);
            a0 += bf2f(v0.x); a1 += bf2f(v0.y);
            a2 += bf2f(v0.z); a3 += bf2f(v0.w);
        }
        if (ok1) {
            const us4 v1 = *reinterpret_cast<const us4*>(
                &m[(size_t)s1 * 256 + lane * 4]);
            a0 += bf2f(v1.x); a1 += bf2f(v1.y);
            a2 += bf2f(v1.z); a3 += bf2f(v1.w);
        }
    }
    if (e < end) {
        const int s0 = bucket[e];
        if ((unsigned)s0 < (unsigned)Nn) {
            const us4 v0 = *reinterpret_cast<const us4*>(
                &m[(size_t)s0 * 256 + lane * 4]);
            a0 += bf2f(v0.x); a1 += bf2f(v0.y);
            a2 += bf2f(v0.z); a3 += bf2f(v0.w);
        }
    }
    us4 o = { f2bf(a0), f2bf(a1), f2bf(a2), f2bf(a3) };
    *reinterpret_cast<us4*>(&out[(size_t)wave * 256 + lane * 4]) = o;
}

extern "C" void kernel_launch(void* const* d_in, const int* in_sizes, int n_in,
                              void* d_out, int out_size, void* d_ws, size_t ws_size,
                              hipStream_t stream)
{
    const float* x      = (const float*)d_in[0];
    const int*   ei     = (const int*)d_in[1];   // [2][E]
    const float* enc_w1 = (const float*)d_in[3];
    const float* enc_b1 = (const float*)d_in[4];
    const float* enc_w2 = (const float*)d_in[5];
    const float* enc_b2 = (const float*)d_in[6];
    const float* msg_w  = (const float*)d_in[7];
    const float* msg_b  = (const float*)d_in[8];
    const float* dec_w1 = (const float*)d_in[9];
    const float* dec_b1 = (const float*)d_in[10];
    const float* dec_w2 = (const float*)d_in[11];
    const float* dec_b2 = (const float*)d_in[12];

    const int N = 50000, D = 128, H = 256;
    const int E = in_sizes[1] / 2;
    const int NB = (N + 255) / 256;   // 196 scan blocks

    // ws layout (u16 part ~141.5 MB, then int CSR part ~2.2 MB; R1 proved
    // >= 153.6 MB usable).
    u16* xb   = (u16*)d_ws;                 // [N,128]
    u16* h1   = xb   + (size_t)N * D;       // [N,256]
    u16* h    = h1   + (size_t)N * H;
    u16* m    = h    + (size_t)N * H;
    u16* aggr = m    + (size_t)N * H;
    u16* dbuf = aggr + (size_t)N * H;
    u16* w_enc1 = dbuf + (size_t)N * H;     // 256*128
    u16* w_enc2 = w_enc1 + 256 * 128;       // 256*256
    u16* w_msg  = w_enc2 + 256 * 256;       // 256*256
    u16* w_dec1 = w_msg  + 256 * 256;       // 256*512
    u16* w_dec2 = w_dec1 + 256 * 512;       // 128*256
    int* deg     = (int*)(w_dec2 + 128 * 256);  // [N]   (4B-aligned: even u16 count)
    int* offsets = deg + N;                 // [N+1]
    int* cursor  = offsets + N + 1;         // [N]
    int* bucket  = cursor + N;              // [E]
    int* bsums   = bucket + E;              // [NB]
    int* bscan   = bsums + NB;              // [NB]

    const dim3 blk(256);
    const dim3 gridH(2, (N + 127) / 128);   // M=256
    const dim3 gridD(1, (N + 127) / 128);   // M=128
    const int eblk = (E + 255) / 256;

    // converts
    cvt_kernel<<<dim3((N * D / 4 + 255) / 256), blk, 0, stream>>>(x, xb, N * D / 4);
    cvt5_kernel<<<dim3((256 * 512 / 4 + 255) / 256, 5), blk, 0, stream>>>(
        enc_w1, enc_w2, msg_w, dec_w1, dec_w2,
        w_enc1, w_enc2, w_msg, w_dec1, w_dec2,
        256 * 128 / 4, 256 * 256 / 4, 256 * 256 / 4, 256 * 512 / 4, 128 * 256 / 4);

    // CSR build
    zero_kernel<<<dim3(NB), blk, 0, stream>>>(deg, N);
    histo_kernel<<<dim3(eblk), blk, 0, stream>>>(ei, deg, E, N);
    scan_reduce_kernel<<<dim3(NB), blk, 0, stream>>>(deg, bsums, N);
    scan_sums_kernel<<<dim3(1), blk, 0, stream>>>(bsums, bscan, NB);
    scan_final_kernel<<<dim3(NB), blk, 0, stream>>>(deg, bscan, offsets,
                                                    cursor, N);
    fill_kernel<<<dim3(eblk), blk, 0, stream>>>(ei, cursor, bucket, E, N);

    // 1) h1 = relu(x @ enc_w1^T + b1)
    gemm_bf16<1, true><<<gridH, blk, 0, stream>>>(xb, xb, D, D, w_enc1, enc_b1,
                                                  h1, N, H);
    // 2) h = relu(h1 @ enc_w2^T + b2)
    gemm_bf16<1, true><<<gridH, blk, 0, stream>>>(h1, h1, H, H, w_enc2, enc_b2,
                                                  h, N, H);
    // 3) m = h @ msg_w^T + msg_b
    gemm_bf16<0, true><<<gridH, blk, 0, stream>>>(h, h, H, H, w_msg, msg_b,
                                                  m, N, H);
    // 4) aggr = segment_sum(m[src], dst)
    gather_sum_kernel<<<dim3((N * 64 + 255) / 256), blk, 0, stream>>>(
        m, bucket, offsets, aggr, N, E);
    // 5) d = relu(cat(aggr, h) @ dec_w1^T + b1), K=512 split at 256
    gemm_bf16<1, true><<<gridH, blk, 0, stream>>>(aggr, h, H, 2 * H, w_dec1,
                                                  dec_b1, dbuf, N, H);
    // 6) out = tanh(d @ dec_w2^T + b2) -- the ONLY write to d_out
    gemm_bf16<2, false><<<gridD, blk, 0, stream>>>(dbuf, dbuf, H, H, w_dec2,
                                                   dec_b2, (float*)d_out, N, D);
}

// Round 6
// 298.248 us; speedup vs baseline: 6.3953x; 1.4255x over previous
//
#include <hip/hip_runtime.h>
#include <cmath>

// GNNCASimple: x:[N,128] -> enc MLP -> h:[N,256] -> msg GEMM -> m:[N,256]
// -> segment_sum over E edges -> aggr:[N,256] -> dec(cat(aggr,h)) -> out:[N,128]
// N=50000, E=400000, D=128, H=256, steps=1.
//
// R2: CSR gather replaced atomic scatter (1907 -> 766 us).
// R3: bf16 MFMA GEMMs + bf16 activations (766 -> 532 us).
// R4/R5: hierarchical scan + CSR scratch moved into d_ws (532 -> 425 us).
// R6: GEMM staging via 16B global_load_lds (async direct-to-LDS, m97 recipe).
//     R5 profile: decoder GEMM 89 us with MfmaUtil 5.6%/VALU 11%/occ 21% --
//     latency-bound on the global->VGPR->LDS round trip.

typedef __attribute__((ext_vector_type(8))) short  short8;   // 8 bf16 (4 VGPR)
typedef __attribute__((ext_vector_type(4))) float  f32x4;    // MFMA acc
typedef __attribute__((ext_vector_type(4))) unsigned short us4;

typedef unsigned short u16;
typedef unsigned int   u32;

static __device__ __forceinline__ u16 f2bf(float f) {
    u32 u = __float_as_uint(f);
    u = (u + 0x7FFFu + ((u >> 16) & 1u)) >> 16;   // round-to-nearest-even
    return (u16)u;
}
static __device__ __forceinline__ float bf2f(u16 h) {
    return __uint_as_float(((u32)h) << 16);
}

// async 16B global -> LDS (one granule lane-slot); lds must be wave-uniform.
static __device__ __forceinline__ void g2l16(const void* g, void* l) {
    __builtin_amdgcn_global_load_lds(
        (const __attribute__((address_space(1))) u32*)g,
        (__attribute__((address_space(3))) u32*)l, 16, 0, 0);
}

// ---------------- bf16 MFMA GEMM ----------------
// C[N,M] = act(A[N,K] @ W[M,K]^T + bias). A = concat(A0 cols [0,K0), A1 rest),
// both bf16. W bf16 [M,K]. bias fp32. ACT: 0=none 1=relu 2=tanh.
// Tile 128x128, BK=32, 256 threads (4 waves, each 64x64 = 4x4 MFMA tiles).
// LDS tiles are LINEAR [128][32] (64 B/row) -- required by global_load_lds's
// wave-uniform-base + lane*16 destination rule (no padding possible).
template <int ACT, bool OUT_BF16>
__global__ __launch_bounds__(256) void gemm_bf16(
    const u16* __restrict__ A0, const u16* __restrict__ A1,
    const int K0, const int K,
    const u16* __restrict__ W, const float* __restrict__ bias,
    void* __restrict__ Cout, const int N, const int M)
{
    __shared__ u16 As[128 * 32];
    __shared__ u16 Ws[128 * 32];

    const int t    = threadIdx.x;
    const int c0   = blockIdx.x * 128;
    const int r0   = blockIdx.y * 128;
    const int wave = t >> 6;
    const int lane = t & 63;
    const int n    = lane & 15;       // fragment row index
    const int q    = lane >> 4;       // k-granule / acc row-quad
    const int wr   = (wave & 1) * 64;
    const int wc   = (wave >> 1) * 64;

    // staging: granule g covers tile rows [16g,16g+16), 1 KB of LDS.
    // wave w owns granules {w, w+4}; lane i -> row 16g+(i>>2), 16B chunk i&3.
    const int grow0 = wave * 16 + (lane >> 2);        // granule w
    const int grow1 = (wave + 4) * 16 + (lane >> 2);  // granule w+4
    const int qofs  = (lane & 3) * 8;                 // bf16 elems within row

    const int KA1 = K - K0;
    // per-lane global base pointers (column offset added per iteration)
    const int ar0 = min(r0 + grow0, N - 1);  // clamp tail (junk OK, masked)
    const int ar1 = min(r0 + grow1, N - 1);
    const u16* a0b0 = A0 + (size_t)ar0 * K0 + qofs;
    const u16* a0b1 = A0 + (size_t)ar1 * K0 + qofs;
    const u16* a1b0 = A1 + (size_t)ar0 * KA1 + qofs;
    const u16* a1b1 = A1 + (size_t)ar1 * KA1 + qofs;
    const u16* wb0  = W + (size_t)(c0 + grow0) * K + qofs;
    const u16* wb1  = W + (size_t)(c0 + grow1) * K + qofs;
    // wave-uniform LDS destinations (u16 units; 1 KB = 512 u16 per granule)
    u16* ldsA0 = &As[wave * 512];
    u16* ldsA1 = &As[(wave + 4) * 512];
    u16* ldsW0 = &Ws[wave * 512];
    u16* ldsW1 = &Ws[(wave + 4) * 512];

    f32x4 acc[4][4];
#pragma unroll
    for (int i = 0; i < 4; i++)
#pragma unroll
        for (int j = 0; j < 4; j++) acc[i][j] = (f32x4)0.0f;

    for (int kc = 0; kc < K; kc += 32) {
        __syncthreads();   // all waves done reading previous tile
        if (kc < K0) {     // uniform branch (K0 multiple of 32)
            g2l16(a0b0 + kc, ldsA0);
            g2l16(a0b1 + kc, ldsA1);
        } else {
            g2l16(a1b0 + (kc - K0), ldsA0);
            g2l16(a1b1 + (kc - K0), ldsA1);
        }
        g2l16(wb0 + kc, ldsW0);
        g2l16(wb1 + kc, ldsW1);
        __syncthreads();   // drains vmcnt: staged data visible

        short8 af[4], bf[4];
#pragma unroll
        for (int i = 0; i < 4; i++)
            af[i] = *reinterpret_cast<const short8*>(
                &As[(wr + i * 16 + n) * 32 + q * 8]);
#pragma unroll
        for (int j = 0; j < 4; j++)
            bf[j] = *reinterpret_cast<const short8*>(
                &Ws[(wc + j * 16 + n) * 32 + q * 8]);
#pragma unroll
        for (int i = 0; i < 4; i++)
#pragma unroll
            for (int j = 0; j < 4; j++)
                acc[i][j] = __builtin_amdgcn_mfma_f32_16x16x32_bf16(
                    af[i], bf[j], acc[i][j], 0, 0, 0);
    }

    float bv[4];
#pragma unroll
    for (int j = 0; j < 4; j++) bv[j] = bias[c0 + wc + j * 16 + n];

#pragma unroll
    for (int i = 0; i < 4; i++) {
        const int rbase = r0 + wr + i * 16 + q * 4;
#pragma unroll
        for (int reg = 0; reg < 4; reg++) {
            const int row = rbase + reg;
            if (row < N) {
#pragma unroll
                for (int j = 0; j < 4; j++) {
                    const int col = c0 + wc + j * 16 + n;
                    float v = acc[i][j][reg] + bv[j];
                    if (ACT == 1) v = fmaxf(v, 0.0f);
                    if (ACT == 2) v = tanhf(v);
                    if (OUT_BF16)
                        ((u16*)Cout)[(size_t)row * M + col] = f2bf(v);
                    else
                        ((float*)Cout)[(size_t)row * M + col] = v;
                }
            }
        }
    }
}

// ---------------- converts ----------------
__global__ __launch_bounds__(256) void cvt_kernel(
    const float* __restrict__ s, u16* __restrict__ d, const int n4)
{
    const int i = blockIdx.x * 256 + threadIdx.x;
    if (i < n4) {
        const float4 v = reinterpret_cast<const float4*>(s)[i];
        us4 o = { f2bf(v.x), f2bf(v.y), f2bf(v.z), f2bf(v.w) };
        reinterpret_cast<us4*>(d)[i] = o;
    }
}

__global__ __launch_bounds__(256) void cvt5_kernel(
    const float* s0, const float* s1, const float* s2, const float* s3,
    const float* s4, u16* d0, u16* d1, u16* d2, u16* d3, u16* d4,
    int n0, int n1, int n2, int n3, int n4)
{
    const float* s; u16* d; int n4c;
    switch (blockIdx.y) {
        case 0: s = s0; d = d0; n4c = n0; break;
        case 1: s = s1; d = d1; n4c = n1; break;
        case 2: s = s2; d = d2; n4c = n2; break;
        case 3: s = s3; d = d3; n4c = n3; break;
        default: s = s4; d = d4; n4c = n4; break;
    }
    const int i = blockIdx.x * 256 + threadIdx.x;
    if (i < n4c) {
        const float4 v = reinterpret_cast<const float4*>(s)[i];
        us4 o = { f2bf(v.x), f2bf(v.y), f2bf(v.z), f2bf(v.w) };
        reinterpret_cast<us4*>(d)[i] = o;
    }
}

// ---------------- CSR build (all scratch in d_ws) ----------------
__global__ __launch_bounds__(256) void zero_kernel(
    int* __restrict__ p, const int n)
{
    const int i = blockIdx.x * 256 + threadIdx.x;
    if (i < n) p[i] = 0;
}

__global__ __launch_bounds__(256) void histo_kernel(
    const int* __restrict__ ei, int* __restrict__ deg, const int E,
    const int Nn)
{
    const int e = blockIdx.x * 256 + threadIdx.x;
    if (e < E) {
        const int dst = ei[(size_t)E + e];
        if ((unsigned)dst < (unsigned)Nn) atomicAdd(&deg[dst], 1);
    }
}

__global__ __launch_bounds__(256) void scan_reduce_kernel(
    const int* __restrict__ deg, int* __restrict__ bsums, const int Nn)
{
    __shared__ int s[256];
    const int t = threadIdx.x;
    const int i = blockIdx.x * 256 + t;
    s[t] = (i < Nn) ? deg[i] : 0;
    __syncthreads();
    for (int d = 128; d > 0; d >>= 1) {
        if (t < d) s[t] += s[t + d];
        __syncthreads();
    }
    if (t == 0) bsums[blockIdx.x] = s[0];
}

__global__ __launch_bounds__(256) void scan_sums_kernel(
    const int* __restrict__ bsums, int* __restrict__ bscan, const int nb)
{
    __shared__ int s[256];
    const int t = threadIdx.x;
    const int v = (t < nb) ? bsums[t] : 0;
    s[t] = v;
    __syncthreads();
    for (int d = 1; d < 256; d <<= 1) {
        int u = (t >= d) ? s[t - d] : 0;
        __syncthreads();
        s[t] += u;
        __syncthreads();
    }
    if (t < nb) bscan[t] = s[t] - v;   // exclusive
}

__global__ __launch_bounds__(256) void scan_final_kernel(
    const int* __restrict__ deg, const int* __restrict__ bscan,
    int* __restrict__ offsets, int* __restrict__ cursor, const int Nn)
{
    __shared__ int s[256];
    const int t = threadIdx.x;
    const int i = blockIdx.x * 256 + t;
    const int v = (i < Nn) ? deg[i] : 0;
    s[t] = v;
    __syncthreads();
    for (int d = 1; d < 256; d <<= 1) {
        int u = (t >= d) ? s[t - d] : 0;
        __syncthreads();
        s[t] += u;
        __syncthreads();
    }
    const int excl = s[t] - v + bscan[blockIdx.x];
    if (i < Nn) {
        offsets[i] = excl;
        cursor[i]  = excl;
        if (i == Nn - 1) offsets[Nn] = excl + v;   // == E
    }
}

__global__ __launch_bounds__(256) void fill_kernel(
    const int* __restrict__ ei, int* __restrict__ cursor,
    int* __restrict__ bucket, const int E, const int Nn)
{
    const int e = blockIdx.x * 256 + threadIdx.x;
    if (e < E) {
        const int src = ei[e];
        const int dst = ei[(size_t)E + e];
        if ((unsigned)dst < (unsigned)Nn) {
            const int pos = atomicAdd(&cursor[dst], 1);
            if ((unsigned)pos < (unsigned)E) bucket[pos] = src;
        }
    }
}

// ---------------- gather-sum (bf16 m -> bf16 aggr) ----------------
__global__ __launch_bounds__(256) void gather_sum_kernel(
    const u16* __restrict__ m, const int* __restrict__ bucket,
    const int* __restrict__ offsets, u16* __restrict__ out,
    const int Nn, const int E)
{
    const int wave = (int)((blockIdx.x * 256u + threadIdx.x) >> 6);
    const int lane = threadIdx.x & 63;
    if (wave >= Nn) return;
    int beg = offsets[wave];
    int end = offsets[wave + 1];
    beg = max(0, min(beg, E));
    end = max(beg, min(end, E));
    float a0 = 0.f, a1 = 0.f, a2 = 0.f, a3 = 0.f;
    int e = beg;
    for (; e + 1 < end; e += 2) {
        const int s0 = bucket[e];
        const int s1 = bucket[e + 1];
        const bool ok0 = (unsigned)s0 < (unsigned)Nn;
        const bool ok1 = (unsigned)s1 < (unsigned)Nn;
        if (ok0) {
            const us4 v0 = *reinterpret_cast<const us4*>(
                &m[(size_t)s0 * 256 + lane * 4]);
            a0 += bf2f(v0.x); a1 += bf2f(v0.y);
            a2 += bf2f(v0.z); a3 += bf2f(v0.w);
        }
        if (ok1) {
            const us4 v1 = *reinterpret_cast<const us4*>(
                &m[(size_t)s1 * 256 + lane * 4]);
            a0 += bf2f(v1.x); a1 += bf2f(v1.y);
            a2 += bf2f(v1.z); a3 += bf2f(v1.w);
        }
    }
    if (e < end) {
        const int s0 = bucket[e];
        if ((unsigned)s0 < (unsigned)Nn) {
            const us4 v0 = *reinterpret_cast<const us4*>(
                &m[(size_t)s0 * 256 + lane * 4]);
            a0 += bf2f(v0.x); a1 += bf2f(v0.y);
            a2 += bf2f(v0.z); a3 += bf2f(v0.w);
        }
    }
    us4 o = { f2bf(a0), f2bf(a1), f2bf(a2), f2bf(a3) };
    *reinterpret_cast<us4*>(&out[(size_t)wave * 256 + lane * 4]) = o;
}

extern "C" void kernel_launch(void* const* d_in, const int* in_sizes, int n_in,
                              void* d_out, int out_size, void* d_ws, size_t ws_size,
                              hipStream_t stream)
{
    const float* x      = (const float*)d_in[0];
    const int*   ei     = (const int*)d_in[1];   // [2][E]
    const float* enc_w1 = (const float*)d_in[3];
    const float* enc_b1 = (const float*)d_in[4];
    const float* enc_w2 = (const float*)d_in[5];
    const float* enc_b2 = (const float*)d_in[6];
    const float* msg_w  = (const float*)d_in[7];
    const float* msg_b  = (const float*)d_in[8];
    const float* dec_w1 = (const float*)d_in[9];
    const float* dec_b1 = (const float*)d_in[10];
    const float* dec_w2 = (const float*)d_in[11];
    const float* dec_b2 = (const float*)d_in[12];

    const int N = 50000, D = 128, H = 256;
    const int E = in_sizes[1] / 2;
    const int NB = (N + 255) / 256;   // 196 scan blocks

    // ws layout (u16 part ~141.5 MB, then int CSR part ~2.2 MB)
    u16* xb   = (u16*)d_ws;                 // [N,128]
    u16* h1   = xb   + (size_t)N * D;       // [N,256]
    u16* h    = h1   + (size_t)N * H;
    u16* m    = h    + (size_t)N * H;
    u16* aggr = m    + (size_t)N * H;
    u16* dbuf = aggr + (size_t)N * H;
    u16* w_enc1 = dbuf + (size_t)N * H;     // 256*128
    u16* w_enc2 = w_enc1 + 256 * 128;       // 256*256
    u16* w_msg  = w_enc2 + 256 * 256;       // 256*256
    u16* w_dec1 = w_msg  + 256 * 256;       // 256*512
    u16* w_dec2 = w_dec1 + 256 * 512;       // 128*256
    int* deg     = (int*)(w_dec2 + 128 * 256);  // [N]
    int* offsets = deg + N;                 // [N+1]
    int* cursor  = offsets + N + 1;         // [N]
    int* bucket  = cursor + N;              // [E]
    int* bsums   = bucket + E;              // [NB]
    int* bscan   = bsums + NB;              // [NB]

    const dim3 blk(256);
    const dim3 gridH(2, (N + 127) / 128);   // M=256
    const dim3 gridD(1, (N + 127) / 128);   // M=128
    const int eblk = (E + 255) / 256;

    // converts
    cvt_kernel<<<dim3((N * D / 4 + 255) / 256), blk, 0, stream>>>(x, xb, N * D / 4);
    cvt5_kernel<<<dim3((256 * 512 / 4 + 255) / 256, 5), blk, 0, stream>>>(
        enc_w1, enc_w2, msg_w, dec_w1, dec_w2,
        w_enc1, w_enc2, w_msg, w_dec1, w_dec2,
        256 * 128 / 4, 256 * 256 / 4, 256 * 256 / 4, 256 * 512 / 4, 128 * 256 / 4);

    // CSR build
    zero_kernel<<<dim3(NB), blk, 0, stream>>>(deg, N);
    histo_kernel<<<dim3(eblk), blk, 0, stream>>>(ei, deg, E, N);
    scan_reduce_kernel<<<dim3(NB), blk, 0, stream>>>(deg, bsums, N);
    scan_sums_kernel<<<dim3(1), blk, 0, stream>>>(bsums, bscan, NB);
    scan_final_kernel<<<dim3(NB), blk, 0, stream>>>(deg, bscan, offsets,
                                                    cursor, N);
    fill_kernel<<<dim3(eblk), blk, 0, stream>>>(ei, cursor, bucket, E, N);

    // 1) h1 = relu(x @ enc_w1^T + b1)
    gemm_bf16<1, true><<<gridH, blk, 0, stream>>>(xb, xb, D, D, w_enc1, enc_b1,
                                                  h1, N, H);
    // 2) h = relu(h1 @ enc_w2^T + b2)
    gemm_bf16<1, true><<<gridH, blk, 0, stream>>>(h1, h1, H, H, w_enc2, enc_b2,
                                                  h, N, H);
    // 3) m = h @ msg_w^T + msg_b
    gemm_bf16<0, true><<<gridH, blk, 0, stream>>>(h, h, H, H, w_msg, msg_b,
                                                  m, N, H);
    // 4) aggr = segment_sum(m[src], dst)
    gather_sum_kernel<<<dim3((N * 64 + 255) / 256), blk, 0, stream>>>(
        m, bucket, offsets, aggr, N, E);
    // 5) d = relu(cat(aggr, h) @ dec_w1^T + b1), K=512 split at 256
    gemm_bf16<1, true><<<gridH, blk, 0, stream>>>(aggr, h, H, 2 * H, w_dec1,
                                                  dec_b1, dbuf, N, H);
    // 6) out = tanh(d @ dec_w2^T + b2) -- the ONLY write to d_out
    gemm_bf16<2, false><<<gridD, blk, 0, stream>>>(dbuf, dbuf, H, H, w_dec2,
                                                   dec_b2, (float*)d_out, N, D);
}

// Round 7
// 284.866 us; speedup vs baseline: 6.6957x; 1.0470x over previous
//
#include <hip/hip_runtime.h>
#include <cmath>

// GNNCASimple: x:[N,128] -> enc MLP -> h:[N,256] -> msg GEMM -> m:[N,256]
// -> segment_sum over E edges -> aggr:[N,256] -> dec(cat(aggr,h)) -> out:[N,128]
// N=50000, E=400000, D=128, H=256, steps=1.
//
// R2: CSR gather replaced atomic scatter (1907 -> 766 us).
// R3: bf16 MFMA GEMMs + bf16 activations (766 -> 532 us).
// R4/R5: hierarchical scan + CSR scratch moved into d_ws (532 -> 425 us).
// R6: 16B global_load_lds staging in GEMMs (425 -> 298 us).
// R7: gather unroll-4 (deeper VMEM queue; gather ran at 2.6 TB/s = its own
//     achieved BW) + GEMM BK=64 (halve the vmcnt(0)+barrier drains that
//     dominate these short K-loops; 32 KB LDS keeps ~5 blocks/CU).

typedef __attribute__((ext_vector_type(8))) short  short8;   // 8 bf16 (4 VGPR)
typedef __attribute__((ext_vector_type(4))) float  f32x4;    // MFMA acc
typedef __attribute__((ext_vector_type(4))) unsigned short us4;

typedef unsigned short u16;
typedef unsigned int   u32;

static __device__ __forceinline__ u16 f2bf(float f) {
    u32 u = __float_as_uint(f);
    u = (u + 0x7FFFu + ((u >> 16) & 1u)) >> 16;   // round-to-nearest-even
    return (u16)u;
}
static __device__ __forceinline__ float bf2f(u16 h) {
    return __uint_as_float(((u32)h) << 16);
}

// async 16B global -> LDS; lds base must be wave-uniform (+ lane*16 implicit).
static __device__ __forceinline__ void g2l16(const void* g, void* l) {
    __builtin_amdgcn_global_load_lds(
        (const __attribute__((address_space(1))) u32*)g,
        (__attribute__((address_space(3))) u32*)l, 16, 0, 0);
}

// ---------------- bf16 MFMA GEMM ----------------
// C[N,M] = act(A[N,K] @ W[M,K]^T + bias). A = concat(A0 cols [0,K0), A1 rest),
// both bf16. W bf16 [M,K]. bias fp32. ACT: 0=none 1=relu 2=tanh.
// Tile 128x128, BK=64, 256 threads (4 waves, each 64x64 = 4x4 MFMA tiles).
// LDS tiles LINEAR [128][64] u16 (granule = 8 rows x 64 cols = 1 KB), as
// required by global_load_lds's wave-uniform-base + lane*16 rule.
template <int ACT, bool OUT_BF16>
__global__ __launch_bounds__(256) void gemm_bf16(
    const u16* __restrict__ A0, const u16* __restrict__ A1,
    const int K0, const int K,
    const u16* __restrict__ W, const float* __restrict__ bias,
    void* __restrict__ Cout, const int N, const int M)
{
    __shared__ u16 As[128 * 64];
    __shared__ u16 Ws[128 * 64];

    const int t    = threadIdx.x;
    const int c0   = blockIdx.x * 128;
    const int r0   = blockIdx.y * 128;
    const int wave = t >> 6;
    const int lane = t & 63;
    const int n    = lane & 15;       // fragment row index
    const int q    = lane >> 4;       // k-granule / acc row-quad
    const int wr   = (wave & 1) * 64;
    const int wc   = (wave >> 1) * 64;

    // staging: granule g = rows [8g, 8g+8) x 64 cols; wave owns g = wave+4k.
    const int lrow = lane >> 3;        // 0..7: row within granule
    const int qofs = (lane & 7) * 8;   // u16 offset within row (16 B chunks)

    const int KA1 = K - K0;
    const u16 *a0p[4], *a1p[4], *wp[4];
    u16 *ldsA[4], *ldsW[4];
#pragma unroll
    for (int k2 = 0; k2 < 4; k2++) {
        const int g    = wave + k2 * 4;
        const int grow = g * 8 + lrow;
        const int arow = min(r0 + grow, N - 1);   // clamp tail (junk, masked)
        a0p[k2] = A0 + (size_t)arow * K0 + qofs;
        a1p[k2] = A1 + (size_t)arow * KA1 + qofs;
        wp[k2]  = W + (size_t)(c0 + grow) * K + qofs;  // M multiple of 128
        ldsA[k2] = &As[g * 512];
        ldsW[k2] = &Ws[g * 512];
    }

    f32x4 acc[4][4];
#pragma unroll
    for (int i = 0; i < 4; i++)
#pragma unroll
        for (int j = 0; j < 4; j++) acc[i][j] = (f32x4)0.0f;

    for (int kc = 0; kc < K; kc += 64) {
        __syncthreads();   // all waves done reading previous tile
        if (kc < K0) {     // uniform (K0 multiple of 64)
#pragma unroll
            for (int k2 = 0; k2 < 4; k2++) g2l16(a0p[k2] + kc, ldsA[k2]);
        } else {
#pragma unroll
            for (int k2 = 0; k2 < 4; k2++) g2l16(a1p[k2] + (kc - K0), ldsA[k2]);
        }
#pragma unroll
        for (int k2 = 0; k2 < 4; k2++) g2l16(wp[k2] + kc, ldsW[k2]);
        __syncthreads();   // drains vmcnt: staged data visible

#pragma unroll
        for (int h = 0; h < 2; h++) {
            short8 af[4], bf[4];
#pragma unroll
            for (int i = 0; i < 4; i++)
                af[i] = *reinterpret_cast<const short8*>(
                    &As[(wr + i * 16 + n) * 64 + h * 32 + q * 8]);
#pragma unroll
            for (int j = 0; j < 4; j++)
                bf[j] = *reinterpret_cast<const short8*>(
                    &Ws[(wc + j * 16 + n) * 64 + h * 32 + q * 8]);
#pragma unroll
            for (int i = 0; i < 4; i++)
#pragma unroll
                for (int j = 0; j < 4; j++)
                    acc[i][j] = __builtin_amdgcn_mfma_f32_16x16x32_bf16(
                        af[i], bf[j], acc[i][j], 0, 0, 0);
        }
    }

    float bv[4];
#pragma unroll
    for (int j = 0; j < 4; j++) bv[j] = bias[c0 + wc + j * 16 + n];

#pragma unroll
    for (int i = 0; i < 4; i++) {
        const int rbase = r0 + wr + i * 16 + q * 4;
#pragma unroll
        for (int reg = 0; reg < 4; reg++) {
            const int row = rbase + reg;
            if (row < N) {
#pragma unroll
                for (int j = 0; j < 4; j++) {
                    const int col = c0 + wc + j * 16 + n;
                    float v = acc[i][j][reg] + bv[j];
                    if (ACT == 1) v = fmaxf(v, 0.0f);
                    if (ACT == 2) v = tanhf(v);
                    if (OUT_BF16)
                        ((u16*)Cout)[(size_t)row * M + col] = f2bf(v);
                    else
                        ((float*)Cout)[(size_t)row * M + col] = v;
                }
            }
        }
    }
}

// ---------------- converts ----------------
__global__ __launch_bounds__(256) void cvt_kernel(
    const float* __restrict__ s, u16* __restrict__ d, const int n4)
{
    const int i = blockIdx.x * 256 + threadIdx.x;
    if (i < n4) {
        const float4 v = reinterpret_cast<const float4*>(s)[i];
        us4 o = { f2bf(v.x), f2bf(v.y), f2bf(v.z), f2bf(v.w) };
        reinterpret_cast<us4*>(d)[i] = o;
    }
}

__global__ __launch_bounds__(256) void cvt5_kernel(
    const float* s0, const float* s1, const float* s2, const float* s3,
    const float* s4, u16* d0, u16* d1, u16* d2, u16* d3, u16* d4,
    int n0, int n1, int n2, int n3, int n4)
{
    const float* s; u16* d; int n4c;
    switch (blockIdx.y) {
        case 0: s = s0; d = d0; n4c = n0; break;
        case 1: s = s1; d = d1; n4c = n1; break;
        case 2: s = s2; d = d2; n4c = n2; break;
        case 3: s = s3; d = d3; n4c = n3; break;
        default: s = s4; d = d4; n4c = n4; break;
    }
    const int i = blockIdx.x * 256 + threadIdx.x;
    if (i < n4c) {
        const float4 v = reinterpret_cast<const float4*>(s)[i];
        us4 o = { f2bf(v.x), f2bf(v.y), f2bf(v.z), f2bf(v.w) };
        reinterpret_cast<us4*>(d)[i] = o;
    }
}

// ---------------- CSR build (all scratch in d_ws) ----------------
__global__ __launch_bounds__(256) void zero_kernel(
    int* __restrict__ p, const int n)
{
    const int i = blockIdx.x * 256 + threadIdx.x;
    if (i < n) p[i] = 0;
}

__global__ __launch_bounds__(256) void histo_kernel(
    const int* __restrict__ ei, int* __restrict__ deg, const int E,
    const int Nn)
{
    const int e = blockIdx.x * 256 + threadIdx.x;
    if (e < E) {
        const int dst = ei[(size_t)E + e];
        if ((unsigned)dst < (unsigned)Nn) atomicAdd(&deg[dst], 1);
    }
}

__global__ __launch_bounds__(256) void scan_reduce_kernel(
    const int* __restrict__ deg, int* __restrict__ bsums, const int Nn)
{
    __shared__ int s[256];
    const int t = threadIdx.x;
    const int i = blockIdx.x * 256 + t;
    s[t] = (i < Nn) ? deg[i] : 0;
    __syncthreads();
    for (int d = 128; d > 0; d >>= 1) {
        if (t < d) s[t] += s[t + d];
        __syncthreads();
    }
    if (t == 0) bsums[blockIdx.x] = s[0];
}

__global__ __launch_bounds__(256) void scan_sums_kernel(
    const int* __restrict__ bsums, int* __restrict__ bscan, const int nb)
{
    __shared__ int s[256];
    const int t = threadIdx.x;
    const int v = (t < nb) ? bsums[t] : 0;
    s[t] = v;
    __syncthreads();
    for (int d = 1; d < 256; d <<= 1) {
        int u = (t >= d) ? s[t - d] : 0;
        __syncthreads();
        s[t] += u;
        __syncthreads();
    }
    if (t < nb) bscan[t] = s[t] - v;   // exclusive
}

__global__ __launch_bounds__(256) void scan_final_kernel(
    const int* __restrict__ deg, const int* __restrict__ bscan,
    int* __restrict__ offsets, int* __restrict__ cursor, const int Nn)
{
    __shared__ int s[256];
    const int t = threadIdx.x;
    const int i = blockIdx.x * 256 + t;
    const int v = (i < Nn) ? deg[i] : 0;
    s[t] = v;
    __syncthreads();
    for (int d = 1; d < 256; d <<= 1) {
        int u = (t >= d) ? s[t - d] : 0;
        __syncthreads();
        s[t] += u;
        __syncthreads();
    }
    const int excl = s[t] - v + bscan[blockIdx.x];
    if (i < Nn) {
        offsets[i] = excl;
        cursor[i]  = excl;
        if (i == Nn - 1) offsets[Nn] = excl + v;   // == E
    }
}

__global__ __launch_bounds__(256) void fill_kernel(
    const int* __restrict__ ei, int* __restrict__ cursor,
    int* __restrict__ bucket, const int E, const int Nn)
{
    const int e = blockIdx.x * 256 + threadIdx.x;
    if (e < E) {
        const int src = ei[e];
        const int dst = ei[(size_t)E + e];
        if ((unsigned)dst < (unsigned)Nn) {
            const int pos = atomicAdd(&cursor[dst], 1);
            if ((unsigned)pos < (unsigned)E) bucket[pos] = src;
        }
    }
}

// ---------------- gather-sum (bf16 m -> bf16 aggr) ----------------
// One wave per destination node; 64 lanes x 4 bf16 = 256 cols.
// Unroll-4: 4 independent row loads in flight (deg ~ Poisson(8)).
__global__ __launch_bounds__(256) void gather_sum_kernel(
    const u16* __restrict__ m, const int* __restrict__ bucket,
    const int* __restrict__ offsets, u16* __restrict__ out,
    const int Nn, const int E)
{
    const int wave = (int)((blockIdx.x * 256u + threadIdx.x) >> 6);
    const int lane = threadIdx.x & 63;
    if (wave >= Nn) return;
    int beg = offsets[wave];
    int end = offsets[wave + 1];
    beg = max(0, min(beg, E));
    end = max(beg, min(end, E));
    float a0 = 0.f, a1 = 0.f, a2 = 0.f, a3 = 0.f;
    int e = beg;
    for (; e + 3 < end; e += 4) {
        int sidx[4];
#pragma unroll
        for (int u = 0; u < 4; u++) sidx[u] = bucket[e + u];
        us4 v[4];
#pragma unroll
        for (int u = 0; u < 4; u++) {
            const int s = ((unsigned)sidx[u] < (unsigned)Nn) ? sidx[u] : 0;
            v[u] = *reinterpret_cast<const us4*>(&m[(size_t)s * 256 + lane * 4]);
        }
#pragma unroll
        for (int u = 0; u < 4; u++) {
            if ((unsigned)sidx[u] < (unsigned)Nn) {
                a0 += bf2f(v[u].x); a1 += bf2f(v[u].y);
                a2 += bf2f(v[u].z); a3 += bf2f(v[u].w);
            }
        }
    }
    for (; e < end; e++) {
        const int s0 = bucket[e];
        if ((unsigned)s0 < (unsigned)Nn) {
            const us4 v0 = *reinterpret_cast<const us4*>(
                &m[(size_t)s0 * 256 + lane * 4]);
            a0 += bf2f(v0.x); a1 += bf2f(v0.y);
            a2 += bf2f(v0.z); a3 += bf2f(v0.w);
        }
    }
    us4 o = { f2bf(a0), f2bf(a1), f2bf(a2), f2bf(a3) };
    *reinterpret_cast<us4*>(&out[(size_t)wave * 256 + lane * 4]) = o;
}

extern "C" void kernel_launch(void* const* d_in, const int* in_sizes, int n_in,
                              void* d_out, int out_size, void* d_ws, size_t ws_size,
                              hipStream_t stream)
{
    const float* x      = (const float*)d_in[0];
    const int*   ei     = (const int*)d_in[1];   // [2][E]
    const float* enc_w1 = (const float*)d_in[3];
    const float* enc_b1 = (const float*)d_in[4];
    const float* enc_w2 = (const float*)d_in[5];
    const float* enc_b2 = (const float*)d_in[6];
    const float* msg_w  = (const float*)d_in[7];
    const float* msg_b  = (const float*)d_in[8];
    const float* dec_w1 = (const float*)d_in[9];
    const float* dec_b1 = (const float*)d_in[10];
    const float* dec_w2 = (const float*)d_in[11];
    const float* dec_b2 = (const float*)d_in[12];

    const int N = 50000, D = 128, H = 256;
    const int E = in_sizes[1] / 2;
    const int NB = (N + 255) / 256;   // 196 scan blocks

    // ws layout (u16 part ~141.5 MB, then int CSR part ~2.2 MB)
    u16* xb   = (u16*)d_ws;                 // [N,128]
    u16* h1   = xb   + (size_t)N * D;       // [N,256]
    u16* h    = h1   + (size_t)N * H;
    u16* m    = h    + (size_t)N * H;
    u16* aggr = m    + (size_t)N * H;
    u16* dbuf = aggr + (size_t)N * H;
    u16* w_enc1 = dbuf + (size_t)N * H;     // 256*128
    u16* w_enc2 = w_enc1 + 256 * 128;       // 256*256
    u16* w_msg  = w_enc2 + 256 * 256;       // 256*256
    u16* w_dec1 = w_msg  + 256 * 256;       // 256*512
    u16* w_dec2 = w_dec1 + 256 * 512;       // 128*256
    int* deg     = (int*)(w_dec2 + 128 * 256);  // [N]
    int* offsets = deg + N;                 // [N+1]
    int* cursor  = offsets + N + 1;         // [N]
    int* bucket  = cursor + N;              // [E]
    int* bsums   = bucket + E;              // [NB]
    int* bscan   = bsums + NB;              // [NB]

    const dim3 blk(256);
    const dim3 gridH(2, (N + 127) / 128);   // M=256
    const dim3 gridD(1, (N + 127) / 128);   // M=128
    const int eblk = (E + 255) / 256;

    // converts
    cvt_kernel<<<dim3((N * D / 4 + 255) / 256), blk, 0, stream>>>(x, xb, N * D / 4);
    cvt5_kernel<<<dim3((256 * 512 / 4 + 255) / 256, 5), blk, 0, stream>>>(
        enc_w1, enc_w2, msg_w, dec_w1, dec_w2,
        w_enc1, w_enc2, w_msg, w_dec1, w_dec2,
        256 * 128 / 4, 256 * 256 / 4, 256 * 256 / 4, 256 * 512 / 4, 128 * 256 / 4);

    // CSR build
    zero_kernel<<<dim3(NB), blk, 0, stream>>>(deg, N);
    histo_kernel<<<dim3(eblk), blk, 0, stream>>>(ei, deg, E, N);
    scan_reduce_kernel<<<dim3(NB), blk, 0, stream>>>(deg, bsums, N);
    scan_sums_kernel<<<dim3(1), blk, 0, stream>>>(bsums, bscan, NB);
    scan_final_kernel<<<dim3(NB), blk, 0, stream>>>(deg, bscan, offsets,
                                                    cursor, N);
    fill_kernel<<<dim3(eblk), blk, 0, stream>>>(ei, cursor, bucket, E, N);

    // 1) h1 = relu(x @ enc_w1^T + b1)
    gemm_bf16<1, true><<<gridH, blk, 0, stream>>>(xb, xb, D, D, w_enc1, enc_b1,
                                                  h1, N, H);
    // 2) h = relu(h1 @ enc_w2^T + b2)
    gemm_bf16<1, true><<<gridH, blk, 0, stream>>>(h1, h1, H, H, w_enc2, enc_b2,
                                                  h, N, H);
    // 3) m = h @ msg_w^T + msg_b
    gemm_bf16<0, true><<<gridH, blk, 0, stream>>>(h, h, H, H, w_msg, msg_b,
                                                  m, N, H);
    // 4) aggr = segment_sum(m[src], dst)
    gather_sum_kernel<<<dim3((N * 64 + 255) / 256), blk, 0, stream>>>(
        m, bucket, offsets, aggr, N, E);
    // 5) d = relu(cat(aggr, h) @ dec_w1^T + b1), K=512 split at 256
    gemm_bf16<1, true><<<gridH, blk, 0, stream>>>(aggr, h, H, 2 * H, w_dec1,
                                                  dec_b1, dbuf, N, H);
    // 6) out = tanh(d @ dec_w2^T + b2) -- the ONLY write to d_out
    gemm_bf16<2, false><<<gridD, blk, 0, stream>>>(dbuf, dbuf, H, H, w_dec2,
                                                   dec_b2, (float*)d_out, N, D);
}